// Round 9
// baseline (218.732 us; speedup 1.0000x reference)
//
#include <hip/hip_runtime.h>

// CfC dose controller: B=4096 sequences, T=512 sequential steps.
// Layers (fan_in, hid): (4,9) (9,6) (6,1); gates ff1, ff2, t (t = ta+tb folded).
// f-space: gate value f = 1/(1 + 2^y), y pre-scaled dot
//   ff gates: y = -2*log2e*a  -> tanh(a) = 2f-1
//   t  gate : y = -  log2e*a  -> sigma(a) = f
// h_true = 2F-1 folded into consumer weights+biases.
//
// R9 = R7 (169us, best) + stall-targeted diffs only:
//   (1) 2-deep x prefetch (xn1,xn2; pointer increment; last 2 steady iters
//       peeled) -> load-to-use cover ~2 iters (~1900cy) > HBM miss ~900cy.
//       R7 had 1-iter cover; vmcnt wait on xv was a prime stall suspect
//       (R6->R7 cut issue 683->522 cy/SIMD-step but stalls ROSE 292->426).
//   (2) dotB (LDS-state only) before dotA (needs xv) so the vmcnt wait
//       lands mid-step, not at its head.
//   (3) no per-iter clamp/64-bit address rebuild for the prefetch.
// R8 lesson: exec-masked few-lane LDS writes beat branchless dump writes
// (dump scatter: conflicts 450K->4.5M, VALUBusy 55->42%, +44us). Reverted.

#define LOG2E 1.44269504088896340736f
#define SMIN  0.001f

static constexpr int BATCH = 4096;
static constexpr int TLEN  = 512;

__device__ __forceinline__ float frcp(float x)  { return __builtin_amdgcn_rcpf(x); }
__device__ __forceinline__ float fexp2(float x) { return __builtin_amdgcn_exp2f(x); }
__device__ __forceinline__ void membar() { asm volatile("" ::: "memory"); }
// DPP: 0x39 quad_perm[1,2,3,0]; 0x4E quad_perm[2,3,0,1]; 0x104 row_shl:4; 0x108 row_shl:8
template<int CTRL>
__device__ __forceinline__ float dppf(float v) {
    return __int_as_float(__builtin_amdgcn_update_dpp(
        0, __float_as_int(v), CTRL, 0xF, 0xF, true));
}

struct Params { const float* p[29]; float* out; };

__global__ __launch_bounds__(256, 2) void cfc_kernel(Params P) {
    const int tid  = threadIdx.x;
    const int lih  = tid & 31;                       // lane within half-wave
    const int half = ((blockIdx.x << 8) + tid) >> 5; // batch element 0..4095
    const int q    = lih >> 2;                       // quad index
    const int s    = lih & 3;                        // slot within quad
    const bool is3  = (lih == 3);                    // L0 neuron-8 f1 holder
    const bool is28 = (lih == 28);                   // SIG lane

    __shared__ float lds[8 * 64];                    // 8 halves x 64 floats
    float* hp = &lds[(tid >> 5) << 6];

    // A (L0) owners -> slots 0..8
    const bool ownA = (s == 0 && q < 8) || is3;
    const int  slA  = is3 ? 8 : q;
    // B owners: L1 (lanes 4j, j<6) -> slots 9..14; L2 (lane 24) -> slot 15;
    //           SIG (lane 28) -> ring slots 32..63
    const bool ownB1 = (s == 0 && q < 6);
    const bool ownB2 = (lih == 24);
    const int  slBfix = ownB1 ? (9 + q) : 15;

    // ---------------- weights: A (layer 0) ----------------------------------
    float wA[13]; float bA = 0.f;
    {
        const float *Wf1 = P.p[1], *Bf1 = P.p[2], *Wf2 = P.p[3], *Bf2 = P.p[4];
        const float *Wa  = P.p[5], *Ba  = P.p[6], *Wb  = P.p[7], *Bb  = P.p[8];
        const float *M   = P.p[9];
        const int  j   = (s == 3) ? 8 : q;
        const int  g   = (s == 3) ? q : s;
        const bool act = (s == 3) ? (q < 3) : (q < 8);
        const float sc = (g == 2) ? -LOG2E : -2.0f * LOG2E;
        float bias = 0.f;
        if (act) bias = sc * ((g == 0) ? Bf1[j] : (g == 1) ? Bf2[j] : (Ba[j] + Bb[j]));
        #pragma unroll
        for (int k = 0; k < 13; ++k) {
            float c = 0.f;
            if (act) {
                const int idx = j * 13 + k;
                const float wv = (g == 0) ? Wf1[idx] * M[idx]
                               : (g == 1) ? Wf2[idx] * M[idx]
                               : (Wa[idx] + Wb[idx]);   // time gates dense
                c = sc * wv;
            }
            if (k < 4) wA[k] = c;
            else       { wA[k] = c + c; bias -= c; }    // f-col: 2c*F + (b-c)
        }
        bA = bias;
    }
    // ---------------- weights: B (merged L1 | L2 | SIG) ----------------------
    float wB[16]; float bB = 0.f;
    #pragma unroll
    for (int k = 0; k < 16; ++k) wB[k] = 0.f;
    if (q < 6 && s < 3) {            // role L1: neuron j=q, gate g=s
        const float *Wf1 = P.p[10], *Bf1 = P.p[11], *Wf2 = P.p[12], *Bf2 = P.p[13];
        const float *Wa  = P.p[14], *Ba  = P.p[15], *Wb  = P.p[16], *Bb  = P.p[17];
        const float *M   = P.p[18];
        const int j = q, g = s;
        const float sc = (g == 2) ? -LOG2E : -2.0f * LOG2E;
        float bias = sc * ((g == 0) ? Bf1[j] : (g == 1) ? Bf2[j] : (Ba[j] + Bb[j]));
        #pragma unroll
        for (int k = 0; k < 15; ++k) {          // cat col k -> position k
            const int idx = j * 15 + k;
            const float wv = (g == 0) ? Wf1[idx] * M[idx]
                           : (g == 1) ? Wf2[idx] * M[idx]
                           : (Wa[idx] + Wb[idx]);
            const float c = sc * wv;
            wB[k] = c + c; bias -= c;
        }
        bB = bias;
    } else if (lih >= 24 && lih < 27) {  // role L2: gate g=lih-24
        const float *Wf1 = P.p[19], *Bf1 = P.p[20], *Wf2 = P.p[21], *Bf2 = P.p[22];
        const float *Wa  = P.p[23], *Ba  = P.p[24], *Wb  = P.p[25], *Bb  = P.p[26];
        const float *M   = P.p[27];
        const int g = lih - 24;
        const float sc = (g == 2) ? -LOG2E : -2.0f * LOG2E;
        float bias = sc * ((g == 0) ? Bf1[0] : (g == 1) ? Bf2[0] : (Ba[0] + Bb[0]));
        #pragma unroll
        for (int k = 0; k < 7; ++k) {           // cat col k -> pos 9+k (k<6), 15 (k==6)
            const float wv = (g == 0) ? Wf1[k] * M[k]
                           : (g == 1) ? Wf2[k] * M[k]
                           : (Wa[k] + Wb[k]);
            const float c = sc * wv;
            const int pos = (k < 6) ? (9 + k) : 15;
            wB[pos] = c + c; bias -= c;
        }
        bB = bias;
    } else if (is28) {                   // role SIG: f = sigmoid(2*F2 - 1)
        wB[15] = -2.0f * LOG2E;
        bB = LOG2E;
    }

    const float sig_scale = P.p[28][0];

    // ---------------- init state board (f-space; h=0 <=> F=0.5) -------------
    if (lih < 16) hp[lih] = 0.5f;
    membar();

    float4 r0 = *(const float4*)(hp + 0);    // F0[0..3]
    float4 r1 = *(const float4*)(hp + 4);    // F0[4..7]
    float4 r2 = *(const float4*)(hp + 8);    // F0[8], F1[0..2]
    float4 r3 = *(const float4*)(hp + 12);   // F1[3..5], F2

    const float4* xp = reinterpret_cast<const float4*>(P.p[0]) + (size_t)half * TLEN;
    float* sigp = P.out + (size_t)half * TLEN + lih;

    auto STEP = [&](const float4 xv, int tS, bool dA, bool dB1, bool dB2, bool dSG) {
        const bool doB = dB1 || dB2 || dSG;
        float dAa = 0.f, dAb = 0.f, dBa = 0.f, dBb = 0.f;
        // ---- dots (consume old state regs); B first: no dependence on xv ----
        if (doB) {
            dBa = fmaf(wB[0],  r0.x, bB);   dBb = wB[1] * r0.y;
            dBa = fmaf(wB[2],  r0.z, dBa);  dBb = fmaf(wB[3],  r0.w, dBb);
            dBa = fmaf(wB[4],  r1.x, dBa);  dBb = fmaf(wB[5],  r1.y, dBb);
            dBa = fmaf(wB[6],  r1.z, dBa);  dBb = fmaf(wB[7],  r1.w, dBb);
            dBa = fmaf(wB[8],  r2.x, dBa);  dBb = fmaf(wB[9],  r2.y, dBb);
            dBa = fmaf(wB[10], r2.z, dBa);  dBb = fmaf(wB[11], r2.w, dBb);
            dBa = fmaf(wB[12], r3.x, dBa);  dBb = fmaf(wB[13], r3.y, dBb);
            dBa = fmaf(wB[14], r3.z, dBa);  dBb = fmaf(wB[15], r3.w, dBb);
        }
        if (dA) {
            dAa = fmaf(wA[0],  xv.x, bA);   dAb = wA[1] * xv.y;
            dAa = fmaf(wA[2],  xv.z, dAa);  dAb = fmaf(wA[3],  xv.w, dAb);
            dAa = fmaf(wA[4],  r0.x, dAa);  dAb = fmaf(wA[5],  r0.y, dAb);
            dAa = fmaf(wA[6],  r0.z, dAa);  dAb = fmaf(wA[7],  r0.w, dAb);
            dAa = fmaf(wA[8],  r1.x, dAa);  dAb = fmaf(wA[9],  r1.y, dAb);
            dAa = fmaf(wA[10], r1.z, dAa);  dAb = fmaf(wA[11], r1.w, dAb);
            dAa = fmaf(wA[12], r2.x, dAa);
        }
        // ---- transform + combine + masked writes ----
        if (dA) {
            const float f   = frcp(1.0f + fexp2(dAa + dAb));
            const float fq1 = dppf<0x39>(f);   // lane 4j <- 4j+1 (f2)
            const float fq2 = dppf<0x4E>(f);   // lane 4j <- 4j+2 (ft)
            const float fr1 = dppf<0x104>(f);  // lane 3  <- 7
            const float fr2 = dppf<0x108>(f);  // lane 3  <- 11
            const float f2v = is3 ? fr1 : fq1;
            const float ftv = is3 ? fr2 : fq2;
            const float FA  = fmaf(ftv, f2v - f, f);
            if (ownA) hp[slA] = FA;
        }
        if (doB) {
            const float f   = frcp(1.0f + fexp2(dBa + dBb));
            const float fq1 = dppf<0x39>(f);
            const float fq2 = dppf<0x4E>(f);
            const float FB  = fmaf(fq2, fq1 - f, f);
            const float wsrc = is28 ? f : FB;            // SIG writes raw sigmoid
            const int   slot = is28 ? (32 + (tS & 31)) : slBfix;
            const bool  pred = (dB1 && ownB1) || (dB2 && ownB2) || (dSG && is28);
            if (pred) hp[slot] = wsrc;
        }
        membar();                                        // LDS write->read order
        r0 = *(const float4*)(hp + 0);
        r1 = *(const float4*)(hp + 4);
        r2 = *(const float4*)(hp + 8);
        r3 = *(const float4*)(hp + 12);
        if (dSG && ((tS & 31) == 31)) {                  // flush sigma ring
            const float fr = hp[32 + lih];
            *sigp = fmaf(sig_scale, fr, SMIN);
            sigp += 32;
        }
    };

    // ---------------- prologue (fill 3-stage skew) ---------------------------
    STEP(xp[0], 0, true, false, false, false);
    STEP(xp[1], 0, true, true,  false, false);
    STEP(xp[2], 0, true, true,  true,  false);

    // ---------------- steady: i=3..508 (tS=0..505), 2-deep x prefetch --------
    float4 xv = xp[3], xn1 = xp[4], xn2 = xp[5];
    const float4* xq = xp + 6;
    for (int tS = 0; tS <= 505; ++tS) {
        STEP(xv, tS, true, true, true, true);
        xv = xn1; xn1 = xn2;
        xn2 = *xq++;                       // loads xp[tS+6] <= xp[511]
    }
    STEP(xv, 506, true, true, true, true); xv = xn1;   // i=509
    STEP(xv, 507, true, true, true, true); xv = xn2;   // i=510
    STEP(xv, 508, true, true, true, true);             // i=511

    // ---------------- epilogue (drain skew) ----------------------------------
    STEP(xv, 509, false, true,  true,  true);   // L1(511), L2(510), sig(509)
    STEP(xv, 510, false, false, true,  true);   // L2(511), sig(510)
    STEP(xv, 511, false, false, false, true);   // sig(511)

    // final states in slot order == output order: [F0 0..8 | F1 0..5 | F2]
    float hsel = r0.x;
    if (lih == 1)  hsel = r0.y;
    if (lih == 2)  hsel = r0.z;
    if (lih == 3)  hsel = r0.w;
    if (lih == 4)  hsel = r1.x;
    if (lih == 5)  hsel = r1.y;
    if (lih == 6)  hsel = r1.z;
    if (lih == 7)  hsel = r1.w;
    if (lih == 8)  hsel = r2.x;
    if (lih == 9)  hsel = r2.y;
    if (lih == 10) hsel = r2.z;
    if (lih == 11) hsel = r2.w;
    if (lih == 12) hsel = r3.x;
    if (lih == 13) hsel = r3.y;
    if (lih == 14) hsel = r3.z;
    if (lih == 15) hsel = r3.w;
    if (lih < 16) {
        float* hx = P.out + (size_t)BATCH * TLEN + (size_t)half * 16 + lih;
        *hx = fmaf(2.0f, hsel, -1.0f);
    }
}

extern "C" void kernel_launch(void* const* d_in, const int* in_sizes, int n_in,
                              void* d_out, int out_size, void* d_ws, size_t ws_size,
                              hipStream_t stream) {
    (void)in_sizes; (void)n_in; (void)out_size; (void)d_ws; (void)ws_size;
    Params P;
    for (int i = 0; i < 29; ++i) P.p[i] = (const float*)d_in[i];
    P.out = (float*)d_out;
    // 4096 batch elements, one per 32-lane half-wave: 512 blocks * 256 threads
    hipLaunchKernelGGL(cfc_kernel, dim3(BATCH / 8), dim3(256), 0, stream, P);
}

// Round 10
// 92.564 us; speedup vs baseline: 2.3630x; 2.3630x over previous
//
#include <hip/hip_runtime.h>

// CfC dose controller: B=4096 sequences, T=512 sequential steps.
// Layers (fan_in, hid): (4,9) (9,6) (6,1); gates ff1, ff2, t (t = ta+tb folded).
// f-space: gate value f = 1/(1 + 2^y), y pre-scaled dot
//   ff gates: y = -2*log2e*a  -> tanh(a) = 2f-1
//   t  gate : y = -  log2e*a  -> sigma(a) = f
// h_true = 2F-1 folded into consumer weights+biases.
//
// R10: LDS-free "one lane = one neuron, all 3 gates in-lane" mapping.
//   R6-R9 hit the shared-LDS-pipe floor: 16 waves/CU x 4 ds_read_b128/step
//   ~= 900 cy/step/CU (matches measured ~975). Fix: 16 lanes per element
//   (4 elems/wave, 1024 waves, 4/CU = 1/SIMD); lane k owns state slot k
//   [F0 x9 | F1 x6 | F2]. Broadcast = 15x v_mov_dpp row_ror within the
//   16-lane row + 48 rotation-ordered fmacs (pure VALU, zero LDS).
//   row_ror direction PROBED at runtime (affects only the setup-time weight
//   permutation -> semantics-proof). Skew kept: L0(i)|L1(i-1)|L2(i-2)|SIG(i-3).
//   SIG = lane15's own pre-commit F; sigma stored predicated; hx coalesced.

#define LOG2E 1.44269504088896340736f
#define SMIN  0.001f

static constexpr int BATCH = 4096;
static constexpr int TLEN  = 512;

__device__ __forceinline__ float frcp(float x)  { return __builtin_amdgcn_rcpf(x); }
__device__ __forceinline__ float fexp2(float x) { return __builtin_amdgcn_exp2f(x); }
template<int CTRL>
__device__ __forceinline__ float dppf(float v) {
    return __int_as_float(__builtin_amdgcn_update_dpp(
        0, __float_as_int(v), CTRL, 0xF, 0xF, true));
}

// one rotation step: vr = F rotated by R within the 16-lane row; 3 fmacs share it
#define ROTSTEP(CTRL, R) { const float vr = dppf<CTRL>(F);                               \
    if ((R) & 1) { a0b = fmaf(w0r[R], vr, a0b); a1b = fmaf(w1r[R], vr, a1b);             \
                   a2b = fmaf(w2r[R], vr, a2b); }                                        \
    else         { a0  = fmaf(w0r[R], vr, a0 ); a1  = fmaf(w1r[R], vr, a1 );             \
                   a2  = fmaf(w2r[R], vr, a2 ); } }

struct Params { const float* p[29]; float* out; };

__global__ __launch_bounds__(256, 1) void cfc_kernel(Params P) {
    const int tid = threadIdx.x;
    const int li  = tid & 15;                        // lane within element group
    const int e   = (blockIdx.x << 4) + (tid >> 4);  // batch element 0..4095

    // runtime probe of row_ror direction (only permutes the weight gather)
    const float got = dppf<0x121>((float)li);        // row_ror:1 on lane-id
    const int   dir = (((int)got) == ((li + 1) & 15)) ? 1 : -1;

    const int role = (li <= 8) ? 0 : (li <= 14 ? 1 : 2);
    const int jn   = (role == 0) ? li : (role == 1 ? li - 9 : 0);

    const float *Wf1, *Bf1, *Wf2, *Bf2, *Wa, *Ba, *Wb, *Bb, *Mk;
    int cat;
    if (role == 0)      { Wf1=P.p[1];  Bf1=P.p[2];  Wf2=P.p[3];  Bf2=P.p[4];
                          Wa=P.p[5];   Ba=P.p[6];   Wb=P.p[7];   Bb=P.p[8];  Mk=P.p[9];  cat=13; }
    else if (role == 1) { Wf1=P.p[10]; Bf1=P.p[11]; Wf2=P.p[12]; Bf2=P.p[13];
                          Wa=P.p[14];  Ba=P.p[15];  Wb=P.p[16];  Bb=P.p[17]; Mk=P.p[18]; cat=15; }
    else                { Wf1=P.p[19]; Bf1=P.p[20]; Wf2=P.p[21]; Bf2=P.p[22];
                          Wa=P.p[23];  Ba=P.p[24];  Wb=P.p[25];  Bb=P.p[26]; Mk=P.p[27]; cat=7;  }

    const float sc01 = -2.0f * LOG2E, sc2 = -LOG2E;
    float b0 = sc01 * Bf1[jn], b1 = sc01 * Wf2[0] * 0.f + sc01 * Bf2[jn], b2 = sc2 * (Ba[jn] + Bb[jn]);

    // x-part weights (role 0 only; zero elsewhere)
    float xw0[4], xw1[4], xw2[4];
    #pragma unroll
    for (int c = 0; c < 4; ++c) {
        float a = 0.f, bq = 0.f, cq = 0.f;
        if (role == 0) {
            const int idx = jn * 13 + c;
            const float m = Mk[idx];
            a  = sc01 * Wf1[idx] * m;
            bq = sc01 * Wf2[idx] * m;
            cq = sc2  * (Wa[idx] + Wb[idx]);
        }
        xw0[c] = a; xw1[c] = bq; xw2[c] = cq;
    }

    // rotation-ordered F-part weights: slot k = (li + dir*r) & 15
    //   role 0: slots 0..8  -> cat col 4+k   (L0 recurrent block)
    //   role 1: slots 0..14 -> cat col k     (L1: h0 then h1)
    //   role 2: slots 9..15 -> cat col k-9 (k<15), 6 (k==15)
    float w0r[16], w1r[16], w2r[16];
    #pragma unroll
    for (int r = 0; r < 16; ++r) {
        const int k = (li + dir * r) & 15;
        int cc = -1;
        if (role == 0)      { if (k <= 8)  cc = 4 + k; }
        else if (role == 1) { if (k <= 14) cc = k; }
        else                { if (k >= 9)  cc = (k == 15) ? 6 : (k - 9); }
        float a = 0.f, bq = 0.f, cq = 0.f;
        if (cc >= 0) {
            const int idx = jn * cat + cc;
            const float m = Mk[idx];
            a  = sc01 * Wf1[idx] * m;
            bq = sc01 * Wf2[idx] * m;
            cq = sc2  * (Wa[idx] + Wb[idx]);
        }
        w0r[r] = a  + a;  b0 -= a;     // f-space fold: 2c*F, bias -= c
        w1r[r] = bq + bq; b1 -= bq;
        w2r[r] = cq + cq; b2 -= cq;
    }

    const float sig_scale = P.p[28][0];

    float F   = 0.5f;                  // own state slot (f-space; h=0 <=> 0.5)
    float sgv = 0.f;

    const float4* xp = reinterpret_cast<const float4*>(P.p[0]) + (size_t)e * TLEN;
    float* op = P.out + (size_t)e * TLEN;

    auto STEP = [&](const float4 xv, bool cA, bool cB, bool cC) {
        // sigma from lane's PRE-commit F (lane 15: F2(t-3))
        sgv = fmaf(sig_scale, frcp(1.0f + fexp2(fmaf(-2.0f * LOG2E, F, LOG2E))), SMIN);
        float a0 = b0, a1 = b1, a2 = b2;
        float a0b = xw0[0] * xv.x, a1b = xw1[0] * xv.x, a2b = xw2[0] * xv.x;
        a0b = fmaf(xw0[1], xv.y, a0b); a1b = fmaf(xw1[1], xv.y, a1b); a2b = fmaf(xw2[1], xv.y, a2b);
        a0b = fmaf(xw0[2], xv.z, a0b); a1b = fmaf(xw1[2], xv.z, a1b); a2b = fmaf(xw2[2], xv.z, a2b);
        a0b = fmaf(xw0[3], xv.w, a0b); a1b = fmaf(xw1[3], xv.w, a1b); a2b = fmaf(xw2[3], xv.w, a2b);
        a0 = fmaf(w0r[0], F, a0); a1 = fmaf(w1r[0], F, a1); a2 = fmaf(w2r[0], F, a2); // r=0 self
        ROTSTEP(0x121, 1)  ROTSTEP(0x122, 2)  ROTSTEP(0x123, 3)  ROTSTEP(0x124, 4)
        ROTSTEP(0x125, 5)  ROTSTEP(0x126, 6)  ROTSTEP(0x127, 7)  ROTSTEP(0x128, 8)
        ROTSTEP(0x129, 9)  ROTSTEP(0x12A, 10) ROTSTEP(0x12B, 11) ROTSTEP(0x12C, 12)
        ROTSTEP(0x12D, 13) ROTSTEP(0x12E, 14) ROTSTEP(0x12F, 15)
        const float y0 = a0 + a0b, y1 = a1 + a1b, y2 = a2 + a2b;
        const float f0 = frcp(1.0f + fexp2(y0));   // ff1
        const float f1 = frcp(1.0f + fexp2(y1));   // ff2
        const float f2 = frcp(1.0f + fexp2(y2));   // t gate
        const float Fn = fmaf(f2, f1 - f0, f0);
        const bool cm = (role == 0) ? cA : ((role == 1) ? cB : cC);
        F = cm ? Fn : F;
    };

    // ---------------- prologue (fill 3-stage skew; no sigma yet) -------------
    STEP(xp[0], true, false, false);
    STEP(xp[1], true, true,  false);
    STEP(xp[2], true, true,  true);

    // ---------------- steady: iters t=3..510, unroll 4, chunk-ahead prefetch -
    float4 xs0 = xp[3], xs1 = xp[4], xs2 = xp[5], xs3 = xp[6];
    for (int m = 0; m < 127; ++m) {
        const int t = 3 + 4 * m;
        int pn = t + 4; if (pn > 508) pn = 508;          // clamp (no OOB)
        const float4 xn0 = xp[pn], xn1 = xp[pn + 1], xn2 = xp[pn + 2], xn3 = xp[pn + 3];
        STEP(xs0, true, true, true); const float s0 = sgv;   // sg(t-3)
        STEP(xs1, true, true, true); const float s1 = sgv;
        STEP(xs2, true, true, true); const float s2 = sgv;
        STEP(xs3, true, true, true); const float s3 = sgv;   // sg(t)
        if (li == 15) { op[t - 3] = s0; op[t - 2] = s1; op[t - 1] = s2; op[t] = s3; }
        xs0 = xn0; xs1 = xn1; xs2 = xn2; xs3 = xn3;
    }
    // iter t=511 (xs3 = x[511])
    STEP(xs3, true, true, true);  const float s508 = sgv;

    // ---------------- epilogue (drain skew; x unused by committing roles) ----
    STEP(xs3, false, true,  true);  const float s509 = sgv;  // h1(511), h2(510)
    STEP(xs3, false, false, true);  const float s510 = sgv;  // h2(511)
    STEP(xs3, false, false, false); const float s511 = sgv;  // sg(511) only
    if (li == 15) { op[508] = s508; op[509] = s509; op[510] = s510; op[511] = s511; }

    // ---------------- hx: each lane owns exactly its slot -> coalesced -------
    P.out[(size_t)BATCH * TLEN + (size_t)e * 16 + li] = fmaf(2.0f, F, -1.0f);
}

extern "C" void kernel_launch(void* const* d_in, const int* in_sizes, int n_in,
                              void* d_out, int out_size, void* d_ws, size_t ws_size,
                              hipStream_t stream) {
    (void)in_sizes; (void)n_in; (void)out_size; (void)d_ws; (void)ws_size;
    Params P;
    for (int i = 0; i < 29; ++i) P.p[i] = (const float*)d_in[i];
    P.out = (float*)d_out;
    // 4096 elements, 16 lanes each: 256 blocks x 256 threads (4 elems/wave)
    hipLaunchKernelGGL(cfc_kernel, dim3(BATCH / 16), dim3(256), 0, stream, P);
}